// Round 3
// baseline (557.819 us; speedup 1.0000x reference)
//
#include <hip/hip_runtime.h>

#define NN 50000
#define EE 800000

typedef short short8 __attribute__((ext_vector_type(8)));
typedef float f32x4 __attribute__((ext_vector_type(4)));

__device__ __forceinline__ float bf2f(unsigned short u){
  union { unsigned int i; float f; } c; c.i = ((unsigned int)u) << 16; return c.f;
}
__device__ __forceinline__ unsigned short f2bf(float f){
  union { float f; unsigned int i; } c; c.f = f;
  unsigned int i = c.i;
  unsigned int r = (i + 0x7FFFu + ((i >> 16) & 1u)) >> 16;
  return (unsigned short)r;
}
// split f32 -> {hi,hi,lo} triple at p
__device__ __forceinline__ void split3(float v, unsigned short* p){
  unsigned short hi = f2bf(v);
  unsigned short lo = f2bf(v - bf2f(hi));
  p[0] = hi; p[1] = hi; p[2] = lo;
}

// ---- edge_index layout probe: int64 (odd int32 words all zero) vs int32 ----
__global__ void k_detect(const int* eidx, int* flag){
  int lane = threadIdx.x;
  int v = eidx[2*lane + 1];
  unsigned long long nz = __ballot(v != 0);
  if (lane == 0) *flag = (nz == 0ULL) ? 1 : 0;
}

__global__ void k_count(const int* eidx, const int* flag, int* cnt){
  int e = blockIdx.x*256 + threadIdx.x;
  if (e >= EE) return;
  int m = *flag;
  int d = m ? eidx[2*(EE + e)] : eidx[EE + e];
  atomicAdd(&cnt[d], 1);
}

__global__ void k_dinv(const int* cnt, float* dinv){
  int i = blockIdx.x*256 + threadIdx.x;
  if (i < NN) dinv[i] = rsqrtf((float)(cnt[i] + 1));
}

__global__ void k_scanA(const int* cnt, int* bsum){
  __shared__ int s[512];
  int tid = threadIdx.x;
  int i = blockIdx.x*512 + tid;
  s[tid] = (i < NN) ? cnt[i] : 0;
  __syncthreads();
  for (int off = 256; off >= 1; off >>= 1){
    if (tid < off) s[tid] += s[tid + off];
    __syncthreads();
  }
  if (tid == 0) bsum[blockIdx.x] = s[0];
}

__global__ void k_scanB(int* bsum, int* row_off){
  __shared__ int s[128];
  int tid = threadIdx.x;
  int v = (tid < 98) ? bsum[tid] : 0;
  s[tid] = v;
  __syncthreads();
  for (int off = 1; off < 128; off <<= 1){
    int t = (tid >= off) ? s[tid - off] : 0;
    __syncthreads();
    s[tid] += t;
    __syncthreads();
  }
  if (tid < 98) bsum[tid] = s[tid] - v;
  if (tid == 0) row_off[NN] = s[127];
}

__global__ void k_scanC(const int* cnt, const int* bsum, int* row_off, int* cursor){
  __shared__ int s[512];
  int tid = threadIdx.x;
  int i = blockIdx.x*512 + tid;
  int v = (i < NN) ? cnt[i] : 0;
  s[tid] = v;
  __syncthreads();
  for (int off = 1; off < 512; off <<= 1){
    int t = (tid >= off) ? s[tid - off] : 0;
    __syncthreads();
    s[tid] += t;
    __syncthreads();
  }
  if (i < NN){
    int val = bsum[blockIdx.x] + s[tid] - v;
    row_off[i] = val;
    cursor[i]  = val;
  }
}

__global__ void k_fill(const int* eidx, const int* flag, int* cursor, int* colv){
  int e = blockIdx.x*256 + threadIdx.x;
  if (e >= EE) return;
  int m = *flag;
  int sv = m ? eidx[2*e]        : eidx[e];
  int d  = m ? eidx[2*(EE + e)] : eidx[EE + e];
  int p = atomicAdd(&cursor[d], 1);
  colv[p] = sv;
}

// ---- B prep: f32 W -> 3-way-split bf16 B' [n][768], per k: {hi, lo, hi} ----
__global__ void k_prepB1(const float* __restrict__ W1, unsigned short* __restrict__ Bt){
  int idx = blockIdx.x*256 + threadIdx.x;
  int n = idx & 255, k = idx >> 8;
  float w = W1[k*256 + n];
  unsigned short hi = f2bf(w);
  unsigned short lo = f2bf(w - bf2f(hi));
  unsigned short* p = Bt + (size_t)n*768 + 3*k;
  p[0] = hi; p[1] = lo; p[2] = hi;
}
__global__ void k_prepB2(const float* __restrict__ Wmu, const float* __restrict__ Wls,
                         unsigned short* __restrict__ Bt){
  int idx = blockIdx.x*256 + threadIdx.x;
  int n = idx & 255, k = idx >> 8;
  float w = (n < 128) ? Wmu[k*128 + n] : Wls[k*128 + (n - 128)];
  unsigned short hi = f2bf(w);
  unsigned short lo = f2bf(w - bf2f(hi));
  unsigned short* p = Bt + (size_t)n*768 + 3*k;
  p[0] = hi; p[1] = lo; p[2] = hi;
}

// ---- A prep: f32 x -> split-bf16 [r][768], per k: {hi, hi, lo} ----
__global__ __launch_bounds__(256) void k_prepA(const float* __restrict__ X,
                                               unsigned short* __restrict__ Asp){
  int gid = blockIdx.x*256 + threadIdx.x;   // NN*64 threads
  int r = gid >> 6, t = gid & 63;
  if (r >= NN) return;
  float4 v = *(const float4*)(X + (size_t)r*256 + t*4);
  __attribute__((aligned(8))) unsigned short sh[12];
  split3(v.x, sh); split3(v.y, sh+3); split3(v.z, sh+6); split3(v.w, sh+9);
  unsigned short* dp = Asp + (size_t)r*768 + t*12;
  *(uint2*)(dp)     = *(const uint2*)(sh);
  *(uint2*)(dp + 4) = *(const uint2*)(sh + 4);
  *(uint2*)(dp + 8) = *(const uint2*)(sh + 8);
}

// ---- 128x128 tile MFMA GEMM, pre-split A and B (K'=768), f32 C out ----
__global__ __launch_bounds__(256) void k_gemm(const unsigned short* __restrict__ Asp,
                                              const unsigned short* __restrict__ Bt,
                                              float* __restrict__ C, int M){
  __shared__ __align__(16) unsigned short sA[128*104];
  __shared__ __align__(16) unsigned short sB[128*104];
  const int tid  = threadIdx.x;
  const int wave = tid >> 6, lane = tid & 63;
  const int wm = wave >> 1, wn = wave & 1;
  const int quad = lane >> 4, l16 = lane & 15;
  const int tM = blockIdx.x, tN = blockIdx.y;

  f32x4 acc[4][4] = {};

  for (int kt = 0; kt < 8; ++kt){
    #pragma unroll
    for (int ii = 0; ii < 6; ++ii){
      int c = tid + 256*ii;           // 0..1535
      int r = c / 12, ch = c % 12;
      int arow = tM*128 + r; if (arow >= M) arow = M-1;
      uint4 av = *(const uint4*)(Asp + (size_t)arow*768 + kt*96 + ch*8);
      *(uint4*)(&sA[r*104 + ch*8]) = av;
      uint4 bv = *(const uint4*)(Bt + (size_t)(tN*128 + r)*768 + kt*96 + ch*8);
      *(uint4*)(&sB[r*104 + ch*8]) = bv;
    }
    __syncthreads();
    #pragma unroll
    for (int s = 0; s < 3; ++s){
      short8 af[4], bfr[4];
      #pragma unroll
      for (int t = 0; t < 4; ++t) af[t]  = *(const short8*)(&sA[(wm*64 + t*16 + l16)*104 + s*32 + quad*8]);
      #pragma unroll
      for (int t = 0; t < 4; ++t) bfr[t] = *(const short8*)(&sB[(wn*64 + t*16 + l16)*104 + s*32 + quad*8]);
      #pragma unroll
      for (int mt = 0; mt < 4; ++mt)
        #pragma unroll
        for (int nt = 0; nt < 4; ++nt)
          acc[mt][nt] = __builtin_amdgcn_mfma_f32_16x16x32_bf16(af[mt], bfr[nt], acc[mt][nt], 0, 0, 0);
    }
    __syncthreads();
  }

  #pragma unroll
  for (int mt = 0; mt < 4; ++mt){
    #pragma unroll
    for (int r = 0; r < 4; ++r){
      int row = tM*128 + wm*64 + mt*16 + quad*4 + r;
      if (row < M){
        #pragma unroll
        for (int nt = 0; nt < 4; ++nt){
          int cc = tN*128 + wn*64 + nt*16 + l16;
          C[(size_t)row*256 + cc] = acc[mt][nt][r];
        }
      }
    }
  }
}

// ---- agg layer1: gather-sum (unroll-4 MLP), +bias, relu, write SPLIT bf16 ----
__global__ __launch_bounds__(256) void k_agg_relu(const float* __restrict__ feat,
    const float* __restrict__ dinv, const int* __restrict__ row_off, const int* __restrict__ colv,
    const float* __restrict__ b1, unsigned short* __restrict__ outsp){
  int i = blockIdx.x*4 + (threadIdx.x >> 6);
  if (i >= NN) return;
  int lane = threadIdx.x & 63;
  int f0 = lane*4;
  float di = dinv[i];
  float w0 = di*di;
  float4 hv = *(const float4*)(feat + (size_t)i*256 + f0);
  float p0 = hv.x*w0, p1 = hv.y*w0, p2 = hv.z*w0, p3 = hv.w*w0;
  float q0=0.f,q1=0.f,q2=0.f,q3=0.f, r0=0.f,r1=0.f,r2=0.f,r3=0.f, t0=0.f,t1=0.f,t2=0.f,t3=0.f;
  int e0 = row_off[i], e1 = row_off[i+1];
  int e = e0;
  for (; e + 4 <= e1; e += 4){
    int s0 = colv[e], s1 = colv[e+1], s2 = colv[e+2], s3 = colv[e+3];
    float wA = dinv[s0]*di, wB = dinv[s1]*di, wC = dinv[s2]*di, wD = dinv[s3]*di;
    float4 v0 = *(const float4*)(feat + (size_t)s0*256 + f0);
    float4 v1 = *(const float4*)(feat + (size_t)s1*256 + f0);
    float4 v2 = *(const float4*)(feat + (size_t)s2*256 + f0);
    float4 v3 = *(const float4*)(feat + (size_t)s3*256 + f0);
    p0 += v0.x*wA; p1 += v0.y*wA; p2 += v0.z*wA; p3 += v0.w*wA;
    q0 += v1.x*wB; q1 += v1.y*wB; q2 += v1.z*wB; q3 += v1.w*wB;
    r0 += v2.x*wC; r1 += v2.y*wC; r2 += v2.z*wC; r3 += v2.w*wC;
    t0 += v3.x*wD; t1 += v3.y*wD; t2 += v3.z*wD; t3 += v3.w*wD;
  }
  for (; e < e1; ++e){
    int s = colv[e];
    float w = dinv[s]*di;
    float4 v = *(const float4*)(feat + (size_t)s*256 + f0);
    p0 += v.x*w; p1 += v.y*w; p2 += v.z*w; p3 += v.w*w;
  }
  float4 bb = *(const float4*)(b1 + f0);
  float o0 = fmaxf(p0+q0+r0+t0 + bb.x, 0.f);
  float o1 = fmaxf(p1+q1+r1+t1 + bb.y, 0.f);
  float o2 = fmaxf(p2+q2+r2+t2 + bb.z, 0.f);
  float o3 = fmaxf(p3+q3+r3+t3 + bb.w, 0.f);
  __attribute__((aligned(8))) unsigned short sh[12];
  split3(o0, sh); split3(o1, sh+3); split3(o2, sh+6); split3(o3, sh+9);
  unsigned short* dp = outsp + (size_t)i*768 + lane*12;
  *(uint2*)(dp)     = *(const uint2*)(sh);
  *(uint2*)(dp + 4) = *(const uint2*)(sh + 4);
  *(uint2*)(dp + 8) = *(const uint2*)(sh + 8);
}

// ---- agg layer2: gather-sum (unroll-4 MLP), +bias, write mu/logstd f32 ----
__global__ __launch_bounds__(256) void k_agg_out(const float* __restrict__ feat,
    const float* __restrict__ dinv, const int* __restrict__ row_off, const int* __restrict__ colv,
    const float* __restrict__ bmu, const float* __restrict__ bls, float* __restrict__ outp){
  int i = blockIdx.x*4 + (threadIdx.x >> 6);
  if (i >= NN) return;
  int lane = threadIdx.x & 63;
  int f0 = lane*4;
  float di = dinv[i];
  float w0 = di*di;
  float4 hv = *(const float4*)(feat + (size_t)i*256 + f0);
  float p0 = hv.x*w0, p1 = hv.y*w0, p2 = hv.z*w0, p3 = hv.w*w0;
  float q0=0.f,q1=0.f,q2=0.f,q3=0.f, r0=0.f,r1=0.f,r2=0.f,r3=0.f, t0=0.f,t1=0.f,t2=0.f,t3=0.f;
  int e0 = row_off[i], e1 = row_off[i+1];
  int e = e0;
  for (; e + 4 <= e1; e += 4){
    int s0 = colv[e], s1 = colv[e+1], s2 = colv[e+2], s3 = colv[e+3];
    float wA = dinv[s0]*di, wB = dinv[s1]*di, wC = dinv[s2]*di, wD = dinv[s3]*di;
    float4 v0 = *(const float4*)(feat + (size_t)s0*256 + f0);
    float4 v1 = *(const float4*)(feat + (size_t)s1*256 + f0);
    float4 v2 = *(const float4*)(feat + (size_t)s2*256 + f0);
    float4 v3 = *(const float4*)(feat + (size_t)s3*256 + f0);
    p0 += v0.x*wA; p1 += v0.y*wA; p2 += v0.z*wA; p3 += v0.w*wA;
    q0 += v1.x*wB; q1 += v1.y*wB; q2 += v1.z*wB; q3 += v1.w*wB;
    r0 += v2.x*wC; r1 += v2.y*wC; r2 += v2.z*wC; r3 += v2.w*wC;
    t0 += v3.x*wD; t1 += v3.y*wD; t2 += v3.z*wD; t3 += v3.w*wD;
  }
  for (; e < e1; ++e){
    int s = colv[e];
    float w = dinv[s]*di;
    float4 v = *(const float4*)(feat + (size_t)s*256 + f0);
    p0 += v.x*w; p1 += v.y*w; p2 += v.z*w; p3 += v.w*w;
  }
  float a0 = p0+q0+r0+t0, a1 = p1+q1+r1+t1, a2 = p2+q2+r2+t2, a3 = p3+q3+r3+t3;
  float4 o;
  if (f0 < 128){
    float4 bb = *(const float4*)(bmu + f0);
    o.x = a0 + bb.x; o.y = a1 + bb.y; o.z = a2 + bb.z; o.w = a3 + bb.w;
    *(float4*)(outp + (size_t)i*128 + f0) = o;
  } else {
    int g = f0 - 128;
    float4 bb = *(const float4*)(bls + g);
    o.x = a0 + bb.x; o.y = a1 + bb.y; o.z = a2 + bb.z; o.w = a3 + bb.w;
    *(float4*)(outp + (size_t)NN*128 + (size_t)i*128 + g) = o;
  }
}

extern "C" void kernel_launch(void* const* d_in, const int* in_sizes, int n_in,
                              void* d_out, int out_size, void* d_ws, size_t ws_size,
                              hipStream_t stream){
  const float* x   = (const float*)d_in[0];
  const int* eidx  = (const int*)d_in[1];
  const float* W1  = (const float*)d_in[2];
  const float* b1  = (const float*)d_in[3];
  const float* Wmu = (const float*)d_in[4];
  const float* bmu = (const float*)d_in[5];
  const float* Wls = (const float*)d_in[6];
  const float* bls = (const float*)d_in[7];
  float* out = (float*)d_out;

  char* ws = (char*)d_ws;
  size_t off = 0;
  auto alloc = [&](size_t bytes)->char*{
    char* p = ws + off; off = (off + bytes + 511) & ~(size_t)511; return p;
  };
  int* cnt      = (int*)alloc(NN*4);
  float* dinv   = (float*)alloc(NN*4);
  int* row_off  = (int*)alloc((NN+1)*4);
  int* cursor   = (int*)alloc(NN*4);
  int* bsum     = (int*)alloc(128*4);
  int* flag     = (int*)alloc(4);
  int* colv     = (int*)alloc(EE*4);
  unsigned short* Bt1 = (unsigned short*)alloc((size_t)256*768*2);
  unsigned short* Bt2 = (unsigned short*)alloc((size_t)256*768*2);
  unsigned short* AspX = (unsigned short*)alloc((size_t)NN*768*2);
  unsigned short* H1sp = (unsigned short*)alloc((size_t)NN*768*2);
  float* h   = (float*)alloc((size_t)NN*256*4);
  float* z   = h;   // h dead after k_agg_relu; reuse for z

  hipMemsetAsync(cnt, 0, NN*4, stream);
  k_detect<<<1, 64, 0, stream>>>(eidx, flag);
  k_count<<<(EE+255)/256, 256, 0, stream>>>(eidx, flag, cnt);
  k_dinv<<<(NN+255)/256, 256, 0, stream>>>(cnt, dinv);
  k_scanA<<<98, 512, 0, stream>>>(cnt, bsum);
  k_scanB<<<1, 128, 0, stream>>>(bsum, row_off);
  k_scanC<<<98, 512, 0, stream>>>(cnt, bsum, row_off, cursor);
  k_fill<<<(EE+255)/256, 256, 0, stream>>>(eidx, flag, cursor, colv);
  k_prepB1<<<256, 256, 0, stream>>>(W1, Bt1);
  k_prepB2<<<256, 256, 0, stream>>>(Wmu, Wls, Bt2);
  k_prepA<<<12500, 256, 0, stream>>>(x, AspX);
  k_gemm<<<dim3(391, 2), 256, 0, stream>>>(AspX, Bt1, h, NN);
  k_agg_relu<<<12500, 256, 0, stream>>>(h, dinv, row_off, colv, b1, H1sp);
  k_gemm<<<dim3(391, 2), 256, 0, stream>>>(H1sp, Bt2, z, NN);
  k_agg_out<<<12500, 256, 0, stream>>>(z, dinv, row_off, colv, bmu, bls, out);
}

// Round 4
// 550.774 us; speedup vs baseline: 1.0128x; 1.0128x over previous
//
#include <hip/hip_runtime.h>

#define NN 50000
#define EE 800000

typedef short short8 __attribute__((ext_vector_type(8)));
typedef float f32x4 __attribute__((ext_vector_type(4)));

__device__ __forceinline__ float bf2f(unsigned short u){
  union { unsigned int i; float f; } c; c.i = ((unsigned int)u) << 16; return c.f;
}
__device__ __forceinline__ unsigned short f2bf(float f){
  union { float f; unsigned int i; } c; c.f = f;
  unsigned int i = c.i;
  unsigned int r = (i + 0x7FFFu + ((i >> 16) & 1u)) >> 16;
  return (unsigned short)r;
}
__device__ __forceinline__ unsigned short f2h(float f){
  _Float16 h = (_Float16)f; unsigned short u; __builtin_memcpy(&u, &h, 2); return u;
}
__device__ __forceinline__ float h2f(unsigned short u){
  _Float16 h; __builtin_memcpy(&h, &u, 2); return (float)h;
}
// split f32 -> {hi,hi,lo} triple at p
__device__ __forceinline__ void split3(float v, unsigned short* p){
  unsigned short hi = f2bf(v);
  unsigned short lo = f2bf(v - bf2f(hi));
  p[0] = hi; p[1] = hi; p[2] = lo;
}

// layout probe helper: returns 1 if edge_index is int64 (odd int32 words zero)
__device__ __forceinline__ int detect_m(const int* eidx, int* sh){
  int t = threadIdx.x;
  if (t < 64){
    int v = eidx[2*t + 1];
    unsigned long long nz = __ballot(v != 0);
    if (t == 0) *sh = (nz == 0ULL) ? 1 : 0;
  }
  __syncthreads();
  return *sh;
}

__global__ void k_count(const int* __restrict__ eidx, int* __restrict__ cnt){
  __shared__ int msh;
  int m = detect_m(eidx, &msh);
  int e = blockIdx.x*256 + threadIdx.x;
  if (e >= EE) return;
  int d = m ? eidx[2*(EE + e)] : eidx[EE + e];
  atomicAdd(&cnt[d], 1);
}

// single-block scan: cnt -> row_off (exclusive), cursor, dinv, row_off[NN]=E
__global__ __launch_bounds__(1024) void k_scan(const int* __restrict__ cnt,
    int* __restrict__ row_off, int* __restrict__ cursor, float* __restrict__ dinv){
  __shared__ int s[1024];
  int tid = threadIdx.x;
  const int PER = (NN + 1023) / 1024;   // 49
  int base = tid * PER;
  int lim = base + PER; if (lim > NN) lim = NN;
  int tot = 0;
  for (int i = base; i < lim; ++i) tot += cnt[i];
  s[tid] = tot;
  __syncthreads();
  // Hillis-Steele inclusive scan over 1024 partials
  for (int off = 1; off < 1024; off <<= 1){
    int t = (tid >= off) ? s[tid - off] : 0;
    __syncthreads();
    s[tid] += t;
    __syncthreads();
  }
  int run = s[tid] - tot;               // exclusive prefix for this thread
  for (int i = base; i < lim; ++i){
    int c = cnt[i];
    row_off[i] = run;
    cursor[i]  = run;
    dinv[i]    = rsqrtf((float)(c + 1));
    run += c;
  }
  if (tid == 1023) row_off[NN] = s[1023];
}

__global__ void k_fill(const int* __restrict__ eidx, int* __restrict__ cursor,
                       int* __restrict__ colv){
  __shared__ int msh;
  int m = detect_m(eidx, &msh);
  int e = blockIdx.x*256 + threadIdx.x;
  if (e >= EE) return;
  int sv = m ? eidx[2*e]        : eidx[e];
  int d  = m ? eidx[2*(EE + e)] : eidx[EE + e];
  int p = atomicAdd(&cursor[d], 1);
  colv[p] = sv;
}

// ---- B prep (both layers): f32 W -> 3-way-split bf16 B' [n][768], per k {hi,lo,hi} ----
__global__ void k_prepB(const float* __restrict__ W1, const float* __restrict__ Wmu,
                        const float* __restrict__ Wls, unsigned short* __restrict__ Bt1,
                        unsigned short* __restrict__ Bt2){
  int gid = blockIdx.x*256 + threadIdx.x;   // 131072
  int idx = gid & 65535;
  int n = idx & 255, k = idx >> 8;
  float w;
  unsigned short* Bt;
  if (gid < 65536){ w = W1[k*256 + n]; Bt = Bt1; }
  else { w = (n < 128) ? Wmu[k*128 + n] : Wls[k*128 + (n - 128)]; Bt = Bt2; }
  unsigned short hi = f2bf(w);
  unsigned short lo = f2bf(w - bf2f(hi));
  unsigned short* p = Bt + (size_t)n*768 + 3*k;
  p[0] = hi; p[1] = lo; p[2] = hi;
}

// ---- A prep: f32 x -> split-bf16 [r][768], per k: {hi, hi, lo} ----
__global__ __launch_bounds__(256) void k_prepA(const float* __restrict__ X,
                                               unsigned short* __restrict__ Asp){
  int gid = blockIdx.x*256 + threadIdx.x;   // NN*64 threads
  int r = gid >> 6, t = gid & 63;
  if (r >= NN) return;
  float4 v = *(const float4*)(X + (size_t)r*256 + t*4);
  __attribute__((aligned(8))) unsigned short sh[12];
  split3(v.x, sh); split3(v.y, sh+3); split3(v.z, sh+6); split3(v.w, sh+9);
  unsigned short* dp = Asp + (size_t)r*768 + t*12;
  *(uint2*)(dp)     = *(const uint2*)(sh);
  *(uint2*)(dp + 4) = *(const uint2*)(sh + 4);
  *(uint2*)(dp + 8) = *(const uint2*)(sh + 8);
}

// ---- 128x128 tile MFMA GEMM, pre-split A and B (K'=768), fp16 C out ----
__global__ __launch_bounds__(256) void k_gemm(const unsigned short* __restrict__ Asp,
                                              const unsigned short* __restrict__ Bt,
                                              unsigned short* __restrict__ C, int M){
  __shared__ __align__(16) unsigned short sA[128*104];
  __shared__ __align__(16) unsigned short sB[128*104];
  const int tid  = threadIdx.x;
  const int wave = tid >> 6, lane = tid & 63;
  const int wm = wave >> 1, wn = wave & 1;
  const int quad = lane >> 4, l16 = lane & 15;
  const int tM = blockIdx.x, tN = blockIdx.y;

  f32x4 acc[4][4] = {};

  for (int kt = 0; kt < 8; ++kt){
    #pragma unroll
    for (int ii = 0; ii < 6; ++ii){
      int c = tid + 256*ii;           // 0..1535
      int r = c / 12, ch = c % 12;
      int arow = tM*128 + r; if (arow >= M) arow = M-1;
      uint4 av = *(const uint4*)(Asp + (size_t)arow*768 + kt*96 + ch*8);
      *(uint4*)(&sA[r*104 + ch*8]) = av;
      uint4 bv = *(const uint4*)(Bt + (size_t)(tN*128 + r)*768 + kt*96 + ch*8);
      *(uint4*)(&sB[r*104 + ch*8]) = bv;
    }
    __syncthreads();
    #pragma unroll
    for (int s = 0; s < 3; ++s){
      short8 af[4], bfr[4];
      #pragma unroll
      for (int t = 0; t < 4; ++t) af[t]  = *(const short8*)(&sA[(wm*64 + t*16 + l16)*104 + s*32 + quad*8]);
      #pragma unroll
      for (int t = 0; t < 4; ++t) bfr[t] = *(const short8*)(&sB[(wn*64 + t*16 + l16)*104 + s*32 + quad*8]);
      #pragma unroll
      for (int mt = 0; mt < 4; ++mt)
        #pragma unroll
        for (int nt = 0; nt < 4; ++nt)
          acc[mt][nt] = __builtin_amdgcn_mfma_f32_16x16x32_bf16(af[mt], bfr[nt], acc[mt][nt], 0, 0, 0);
    }
    __syncthreads();
  }

  #pragma unroll
  for (int mt = 0; mt < 4; ++mt){
    #pragma unroll
    for (int r = 0; r < 4; ++r){
      int row = tM*128 + wm*64 + mt*16 + quad*4 + r;
      if (row < M){
        #pragma unroll
        for (int nt = 0; nt < 4; ++nt){
          int cc = tN*128 + wn*64 + nt*16 + l16;
          C[(size_t)row*256 + cc] = f2h(acc[mt][nt][r]);
        }
      }
    }
  }
}

// ---- agg layer1: fp16 gather-sum, +bias, relu, write SPLIT bf16 ----
__global__ __launch_bounds__(256) void k_agg_relu(const unsigned short* __restrict__ feat,
    const float* __restrict__ dinv, const int* __restrict__ row_off, const int* __restrict__ colv,
    const float* __restrict__ b1, unsigned short* __restrict__ outsp){
  int i = blockIdx.x*4 + (threadIdx.x >> 6);
  if (i >= NN) return;
  int lane = threadIdx.x & 63;
  int f0 = lane*4;
  float di = dinv[i];
  float w0 = di*di;
  ushort4 hv = *(const ushort4*)(feat + (size_t)i*256 + f0);
  float p0 = h2f(hv.x)*w0, p1 = h2f(hv.y)*w0, p2 = h2f(hv.z)*w0, p3 = h2f(hv.w)*w0;
  float q0=0.f,q1=0.f,q2=0.f,q3=0.f, r0=0.f,r1=0.f,r2=0.f,r3=0.f, t0=0.f,t1=0.f,t2=0.f,t3=0.f;
  int e0 = row_off[i], e1 = row_off[i+1];
  int e = e0;
  for (; e + 4 <= e1; e += 4){
    int s0 = colv[e], s1 = colv[e+1], s2 = colv[e+2], s3 = colv[e+3];
    float wA = dinv[s0]*di, wB = dinv[s1]*di, wC = dinv[s2]*di, wD = dinv[s3]*di;
    ushort4 v0 = *(const ushort4*)(feat + (size_t)s0*256 + f0);
    ushort4 v1 = *(const ushort4*)(feat + (size_t)s1*256 + f0);
    ushort4 v2 = *(const ushort4*)(feat + (size_t)s2*256 + f0);
    ushort4 v3 = *(const ushort4*)(feat + (size_t)s3*256 + f0);
    p0 += h2f(v0.x)*wA; p1 += h2f(v0.y)*wA; p2 += h2f(v0.z)*wA; p3 += h2f(v0.w)*wA;
    q0 += h2f(v1.x)*wB; q1 += h2f(v1.y)*wB; q2 += h2f(v1.z)*wB; q3 += h2f(v1.w)*wB;
    r0 += h2f(v2.x)*wC; r1 += h2f(v2.y)*wC; r2 += h2f(v2.z)*wC; r3 += h2f(v2.w)*wC;
    t0 += h2f(v3.x)*wD; t1 += h2f(v3.y)*wD; t2 += h2f(v3.z)*wD; t3 += h2f(v3.w)*wD;
  }
  for (; e < e1; ++e){
    int s = colv[e];
    float w = dinv[s]*di;
    ushort4 v = *(const ushort4*)(feat + (size_t)s*256 + f0);
    p0 += h2f(v.x)*w; p1 += h2f(v.y)*w; p2 += h2f(v.z)*w; p3 += h2f(v.w)*w;
  }
  float4 bb = *(const float4*)(b1 + f0);
  float o0 = fmaxf(p0+q0+r0+t0 + bb.x, 0.f);
  float o1 = fmaxf(p1+q1+r1+t1 + bb.y, 0.f);
  float o2 = fmaxf(p2+q2+r2+t2 + bb.z, 0.f);
  float o3 = fmaxf(p3+q3+r3+t3 + bb.w, 0.f);
  __attribute__((aligned(8))) unsigned short sh[12];
  split3(o0, sh); split3(o1, sh+3); split3(o2, sh+6); split3(o3, sh+9);
  unsigned short* dp = outsp + (size_t)i*768 + lane*12;
  *(uint2*)(dp)     = *(const uint2*)(sh);
  *(uint2*)(dp + 4) = *(const uint2*)(sh + 4);
  *(uint2*)(dp + 8) = *(const uint2*)(sh + 8);
}

// ---- agg layer2: fp16 gather-sum, +bias, write mu/logstd f32 ----
__global__ __launch_bounds__(256) void k_agg_out(const unsigned short* __restrict__ feat,
    const float* __restrict__ dinv, const int* __restrict__ row_off, const int* __restrict__ colv,
    const float* __restrict__ bmu, const float* __restrict__ bls, float* __restrict__ outp){
  int i = blockIdx.x*4 + (threadIdx.x >> 6);
  if (i >= NN) return;
  int lane = threadIdx.x & 63;
  int f0 = lane*4;
  float di = dinv[i];
  float w0 = di*di;
  ushort4 hv = *(const ushort4*)(feat + (size_t)i*256 + f0);
  float p0 = h2f(hv.x)*w0, p1 = h2f(hv.y)*w0, p2 = h2f(hv.z)*w0, p3 = h2f(hv.w)*w0;
  float q0=0.f,q1=0.f,q2=0.f,q3=0.f, r0=0.f,r1=0.f,r2=0.f,r3=0.f, t0=0.f,t1=0.f,t2=0.f,t3=0.f;
  int e0 = row_off[i], e1 = row_off[i+1];
  int e = e0;
  for (; e + 4 <= e1; e += 4){
    int s0 = colv[e], s1 = colv[e+1], s2 = colv[e+2], s3 = colv[e+3];
    float wA = dinv[s0]*di, wB = dinv[s1]*di, wC = dinv[s2]*di, wD = dinv[s3]*di;
    ushort4 v0 = *(const ushort4*)(feat + (size_t)s0*256 + f0);
    ushort4 v1 = *(const ushort4*)(feat + (size_t)s1*256 + f0);
    ushort4 v2 = *(const ushort4*)(feat + (size_t)s2*256 + f0);
    ushort4 v3 = *(const ushort4*)(feat + (size_t)s3*256 + f0);
    p0 += h2f(v0.x)*wA; p1 += h2f(v0.y)*wA; p2 += h2f(v0.z)*wA; p3 += h2f(v0.w)*wA;
    q0 += h2f(v1.x)*wB; q1 += h2f(v1.y)*wB; q2 += h2f(v1.z)*wB; q3 += h2f(v1.w)*wB;
    r0 += h2f(v2.x)*wC; r1 += h2f(v2.y)*wC; r2 += h2f(v2.z)*wC; r3 += h2f(v2.w)*wC;
    t0 += h2f(v3.x)*wD; t1 += h2f(v3.y)*wD; t2 += h2f(v3.z)*wD; t3 += h2f(v3.w)*wD;
  }
  for (; e < e1; ++e){
    int s = colv[e];
    float w = dinv[s]*di;
    ushort4 v = *(const ushort4*)(feat + (size_t)s*256 + f0);
    p0 += h2f(v.x)*w; p1 += h2f(v.y)*w; p2 += h2f(v.z)*w; p3 += h2f(v.w)*w;
  }
  float a0 = p0+q0+r0+t0, a1 = p1+q1+r1+t1, a2 = p2+q2+r2+t2, a3 = p3+q3+r3+t3;
  float4 o;
  if (f0 < 128){
    float4 bb = *(const float4*)(bmu + f0);
    o.x = a0 + bb.x; o.y = a1 + bb.y; o.z = a2 + bb.z; o.w = a3 + bb.w;
    *(float4*)(outp + (size_t)i*128 + f0) = o;
  } else {
    int g = f0 - 128;
    float4 bb = *(const float4*)(bls + g);
    o.x = a0 + bb.x; o.y = a1 + bb.y; o.z = a2 + bb.z; o.w = a3 + bb.w;
    *(float4*)(outp + (size_t)NN*128 + (size_t)i*128 + g) = o;
  }
}

extern "C" void kernel_launch(void* const* d_in, const int* in_sizes, int n_in,
                              void* d_out, int out_size, void* d_ws, size_t ws_size,
                              hipStream_t stream){
  const float* x   = (const float*)d_in[0];
  const int* eidx  = (const int*)d_in[1];
  const float* W1  = (const float*)d_in[2];
  const float* b1  = (const float*)d_in[3];
  const float* Wmu = (const float*)d_in[4];
  const float* bmu = (const float*)d_in[5];
  const float* Wls = (const float*)d_in[6];
  const float* bls = (const float*)d_in[7];
  float* out = (float*)d_out;

  char* ws = (char*)d_ws;
  size_t off = 0;
  auto alloc = [&](size_t bytes)->char*{
    char* p = ws + off; off = (off + bytes + 511) & ~(size_t)511; return p;
  };
  int* cnt      = (int*)alloc(NN*4);
  float* dinv   = (float*)alloc(NN*4);
  int* row_off  = (int*)alloc((NN+1)*4);
  int* cursor   = (int*)alloc(NN*4);
  int* colv     = (int*)alloc(EE*4);
  unsigned short* Bt1 = (unsigned short*)alloc((size_t)256*768*2);
  unsigned short* Bt2 = (unsigned short*)alloc((size_t)256*768*2);
  unsigned short* AspX = (unsigned short*)alloc((size_t)NN*768*2);
  unsigned short* H1sp = (unsigned short*)alloc((size_t)NN*768*2);
  unsigned short* h = (unsigned short*)alloc((size_t)NN*256*2);  // fp16
  unsigned short* z = h;   // h dead after k_agg_relu; reuse for z

  hipMemsetAsync(cnt, 0, NN*4, stream);
  k_count<<<(EE+255)/256, 256, 0, stream>>>(eidx, cnt);
  k_scan<<<1, 1024, 0, stream>>>(cnt, row_off, cursor, dinv);
  k_fill<<<(EE+255)/256, 256, 0, stream>>>(eidx, cursor, colv);
  k_prepB<<<512, 256, 0, stream>>>(W1, Wmu, Wls, Bt1, Bt2);
  k_prepA<<<12500, 256, 0, stream>>>(x, AspX);
  k_gemm<<<dim3(391, 2), 256, 0, stream>>>(AspX, Bt1, h, NN);
  k_agg_relu<<<12500, 256, 0, stream>>>(h, dinv, row_off, colv, b1, H1sp);
  k_gemm<<<dim3(391, 2), 256, 0, stream>>>(H1sp, Bt2, z, NN);
  k_agg_out<<<12500, 256, 0, stream>>>(z, dinv, row_off, colv, bmu, bls, out);
}

// Round 5
// 397.042 us; speedup vs baseline: 1.4049x; 1.3872x over previous
//
#include <hip/hip_runtime.h>

#define NN 50000
#define EE 800000

typedef _Float16 half8 __attribute__((ext_vector_type(8)));
typedef float f32x4 __attribute__((ext_vector_type(4)));

__device__ __forceinline__ unsigned short f2h(float f){
  _Float16 h = (_Float16)f; unsigned short u; __builtin_memcpy(&u, &h, 2); return u;
}
__device__ __forceinline__ float h2f(unsigned short u){
  _Float16 h; __builtin_memcpy(&h, &u, 2); return (float)h;
}
// split f32 -> interleaved fp16 {hi, lo} at p (hi+lo == v to ~2^-24 rel)
__device__ __forceinline__ void split2h(float v, unsigned short* p){
  _Float16 hi = (_Float16)v;
  _Float16 lo = (_Float16)(v - (float)hi);
  __builtin_memcpy(p, &hi, 2);
  __builtin_memcpy(p+1, &lo, 2);
}

// layout probe helper: returns 1 if edge_index is int64 (odd int32 words zero)
__device__ __forceinline__ int detect_m(const int* eidx, int* sh){
  int t = threadIdx.x;
  if (t < 64){
    int v = eidx[2*t + 1];
    unsigned long long nz = __ballot(v != 0);
    if (t == 0) *sh = (nz == 0ULL) ? 1 : 0;
  }
  __syncthreads();
  return *sh;
}

__global__ void k_count(const int* __restrict__ eidx, int* __restrict__ cnt){
  __shared__ int msh;
  int m = detect_m(eidx, &msh);
  int e = blockIdx.x*256 + threadIdx.x;
  if (e >= EE) return;
  int d = m ? eidx[2*(EE + e)] : eidx[EE + e];
  atomicAdd(&cnt[d], 1);
}

// ---- 3-stage multi-block scan (fast path; single-block version was 134us) ----
__global__ void k_scanA(const int* __restrict__ cnt, int* __restrict__ bsum){
  __shared__ int s[512];
  int tid = threadIdx.x;
  int i = blockIdx.x*512 + tid;
  s[tid] = (i < NN) ? cnt[i] : 0;
  __syncthreads();
  for (int off = 256; off >= 1; off >>= 1){
    if (tid < off) s[tid] += s[tid + off];
    __syncthreads();
  }
  if (tid == 0) bsum[blockIdx.x] = s[0];
}

__global__ void k_scanB(int* bsum, int* row_off){
  __shared__ int s[128];
  int tid = threadIdx.x;
  int v = (tid < 98) ? bsum[tid] : 0;
  s[tid] = v;
  __syncthreads();
  for (int off = 1; off < 128; off <<= 1){
    int t = (tid >= off) ? s[tid - off] : 0;
    __syncthreads();
    s[tid] += t;
    __syncthreads();
  }
  if (tid < 98) bsum[tid] = s[tid] - v;      // exclusive block offsets
  if (tid == 0) row_off[NN] = s[127];        // total = E
}

__global__ void k_scanC(const int* __restrict__ cnt, const int* __restrict__ bsum,
                        int* __restrict__ row_off, int* __restrict__ cursor,
                        float* __restrict__ dinv){
  __shared__ int s[512];
  int tid = threadIdx.x;
  int i = blockIdx.x*512 + tid;
  int v = (i < NN) ? cnt[i] : 0;
  s[tid] = v;
  __syncthreads();
  for (int off = 1; off < 512; off <<= 1){
    int t = (tid >= off) ? s[tid - off] : 0;
    __syncthreads();
    s[tid] += t;
    __syncthreads();
  }
  if (i < NN){
    int val = bsum[blockIdx.x] + s[tid] - v;
    row_off[i] = val;
    cursor[i]  = val;
    dinv[i]    = rsqrtf((float)(v + 1));
  }
}

__global__ void k_fill(const int* __restrict__ eidx, int* __restrict__ cursor,
                       int* __restrict__ colv){
  __shared__ int msh;
  int m = detect_m(eidx, &msh);
  int e = blockIdx.x*256 + threadIdx.x;
  if (e >= EE) return;
  int sv = m ? eidx[2*e]        : eidx[e];
  int d  = m ? eidx[2*(EE + e)] : eidx[EE + e];
  int p = atomicAdd(&cursor[d], 1);
  colv[p] = sv;
}

// ---- B prep (both layers): f32 W -> fp16 duplicated pairs B'[n][512], per k {h,h} ----
__global__ void k_prepB(const float* __restrict__ W1, const float* __restrict__ Wmu,
                        const float* __restrict__ Wls, unsigned short* __restrict__ Bt1,
                        unsigned short* __restrict__ Bt2){
  int gid = blockIdx.x*256 + threadIdx.x;   // 131072
  int idx = gid & 65535;
  int n = idx & 255, k = idx >> 8;
  float w;
  unsigned short* Bt;
  if (gid < 65536){ w = W1[k*256 + n]; Bt = Bt1; }
  else { w = (n < 128) ? Wmu[k*128 + n] : Wls[k*128 + (n - 128)]; Bt = Bt2; }
  unsigned short h = f2h(w);
  unsigned short* p = Bt + (size_t)n*512 + 2*k;
  p[0] = h; p[1] = h;
}

// ---- A prep: f32 x -> interleaved fp16-split [r][512], per k {hi,lo} ----
__global__ __launch_bounds__(256) void k_prepA(const float* __restrict__ X,
                                               unsigned short* __restrict__ Asp){
  int gid = blockIdx.x*256 + threadIdx.x;   // NN*64 threads
  int r = gid >> 6, t = gid & 63;
  if (r >= NN) return;
  float4 v = *(const float4*)(X + (size_t)r*256 + t*4);
  __attribute__((aligned(16))) unsigned short sh[8];
  split2h(v.x, sh); split2h(v.y, sh+2); split2h(v.z, sh+4); split2h(v.w, sh+6);
  *(uint4*)(Asp + (size_t)r*512 + t*8) = *(const uint4*)(sh);
}

// ---- 128x128 tile MFMA GEMM, fp16 split pairs (K'=512), fp16 C out ----
// A'[2k]=hiA, A'[2k+1]=loA ; B'[2k]=B'[2k+1]=fp16(w). One mfma_f16 sums exact A*fp16(B).
__global__ __launch_bounds__(256) void k_gemm(const unsigned short* __restrict__ Asp,
                                              const unsigned short* __restrict__ Bt,
                                              unsigned short* __restrict__ C, int M){
  __shared__ __align__(16) unsigned short sA[128*72];
  __shared__ __align__(16) unsigned short sB[128*72];
  const int tid  = threadIdx.x;
  const int wave = tid >> 6, lane = tid & 63;
  const int wm = wave >> 1, wn = wave & 1;
  const int quad = lane >> 4, l16 = lane & 15;
  const int tM = blockIdx.x, tN = blockIdx.y;

  f32x4 acc[4][4] = {};

  for (int kt = 0; kt < 8; ++kt){
    #pragma unroll
    for (int ii = 0; ii < 4; ++ii){
      int c = tid + 256*ii;           // 0..1023
      int r = c >> 3, ch = c & 7;
      int arow = tM*128 + r; if (arow >= M) arow = M-1;
      uint4 av = *(const uint4*)(Asp + (size_t)arow*512 + kt*64 + ch*8);
      *(uint4*)(&sA[r*72 + ch*8]) = av;
      uint4 bv = *(const uint4*)(Bt + (size_t)(tN*128 + r)*512 + kt*64 + ch*8);
      *(uint4*)(&sB[r*72 + ch*8]) = bv;
    }
    __syncthreads();
    #pragma unroll
    for (int ks = 0; ks < 2; ++ks){
      half8 af[4], bfr[4];
      #pragma unroll
      for (int t = 0; t < 4; ++t) af[t]  = *(const half8*)(&sA[(wm*64 + t*16 + l16)*72 + ks*32 + quad*8]);
      #pragma unroll
      for (int t = 0; t < 4; ++t) bfr[t] = *(const half8*)(&sB[(wn*64 + t*16 + l16)*72 + ks*32 + quad*8]);
      #pragma unroll
      for (int mt = 0; mt < 4; ++mt)
        #pragma unroll
        for (int nt = 0; nt < 4; ++nt)
          acc[mt][nt] = __builtin_amdgcn_mfma_f32_16x16x32_f16(af[mt], bfr[nt], acc[mt][nt], 0, 0, 0);
    }
    __syncthreads();
  }

  #pragma unroll
  for (int mt = 0; mt < 4; ++mt){
    #pragma unroll
    for (int r = 0; r < 4; ++r){
      int row = tM*128 + wm*64 + mt*16 + quad*4 + r;
      if (row < M){
        #pragma unroll
        for (int nt = 0; nt < 4; ++nt){
          int cc = tN*128 + wn*64 + nt*16 + l16;
          C[(size_t)row*256 + cc] = f2h(acc[mt][nt][r]);
        }
      }
    }
  }
}

// ---- agg layer1: fp16 gather-sum, +bias, relu, write fp16-split pairs ----
__global__ __launch_bounds__(256) void k_agg_relu(const unsigned short* __restrict__ feat,
    const float* __restrict__ dinv, const int* __restrict__ row_off, const int* __restrict__ colv,
    const float* __restrict__ b1, unsigned short* __restrict__ outsp){
  int i = blockIdx.x*4 + (threadIdx.x >> 6);
  if (i >= NN) return;
  int lane = threadIdx.x & 63;
  int f0 = lane*4;
  float di = dinv[i];
  float w0 = di*di;
  ushort4 hv = *(const ushort4*)(feat + (size_t)i*256 + f0);
  float p0 = h2f(hv.x)*w0, p1 = h2f(hv.y)*w0, p2 = h2f(hv.z)*w0, p3 = h2f(hv.w)*w0;
  float q0=0.f,q1=0.f,q2=0.f,q3=0.f, r0=0.f,r1=0.f,r2=0.f,r3=0.f, t0=0.f,t1=0.f,t2=0.f,t3=0.f;
  int e0 = row_off[i], e1 = row_off[i+1];
  int e = e0;
  for (; e + 4 <= e1; e += 4){
    int s0 = colv[e], s1 = colv[e+1], s2 = colv[e+2], s3 = colv[e+3];
    float wA = dinv[s0]*di, wB = dinv[s1]*di, wC = dinv[s2]*di, wD = dinv[s3]*di;
    ushort4 v0 = *(const ushort4*)(feat + (size_t)s0*256 + f0);
    ushort4 v1 = *(const ushort4*)(feat + (size_t)s1*256 + f0);
    ushort4 v2 = *(const ushort4*)(feat + (size_t)s2*256 + f0);
    ushort4 v3 = *(const ushort4*)(feat + (size_t)s3*256 + f0);
    p0 += h2f(v0.x)*wA; p1 += h2f(v0.y)*wA; p2 += h2f(v0.z)*wA; p3 += h2f(v0.w)*wA;
    q0 += h2f(v1.x)*wB; q1 += h2f(v1.y)*wB; q2 += h2f(v1.z)*wB; q3 += h2f(v1.w)*wB;
    r0 += h2f(v2.x)*wC; r1 += h2f(v2.y)*wC; r2 += h2f(v2.z)*wC; r3 += h2f(v2.w)*wC;
    t0 += h2f(v3.x)*wD; t1 += h2f(v3.y)*wD; t2 += h2f(v3.z)*wD; t3 += h2f(v3.w)*wD;
  }
  for (; e < e1; ++e){
    int s = colv[e];
    float w = dinv[s]*di;
    ushort4 v = *(const ushort4*)(feat + (size_t)s*256 + f0);
    p0 += h2f(v.x)*w; p1 += h2f(v.y)*w; p2 += h2f(v.z)*w; p3 += h2f(v.w)*w;
  }
  float4 bb = *(const float4*)(b1 + f0);
  float o0 = fmaxf(p0+q0+r0+t0 + bb.x, 0.f);
  float o1 = fmaxf(p1+q1+r1+t1 + bb.y, 0.f);
  float o2 = fmaxf(p2+q2+r2+t2 + bb.z, 0.f);
  float o3 = fmaxf(p3+q3+r3+t3 + bb.w, 0.f);
  __attribute__((aligned(16))) unsigned short sh[8];
  split2h(o0, sh); split2h(o1, sh+2); split2h(o2, sh+4); split2h(o3, sh+6);
  *(uint4*)(outsp + (size_t)i*512 + lane*8) = *(const uint4*)(sh);
}

// ---- agg layer2: fp16 gather-sum, +bias, write mu/logstd f32 ----
__global__ __launch_bounds__(256) void k_agg_out(const unsigned short* __restrict__ feat,
    const float* __restrict__ dinv, const int* __restrict__ row_off, const int* __restrict__ colv,
    const float* __restrict__ bmu, const float* __restrict__ bls, float* __restrict__ outp){
  int i = blockIdx.x*4 + (threadIdx.x >> 6);
  if (i >= NN) return;
  int lane = threadIdx.x & 63;
  int f0 = lane*4;
  float di = dinv[i];
  float w0 = di*di;
  ushort4 hv = *(const ushort4*)(feat + (size_t)i*256 + f0);
  float p0 = h2f(hv.x)*w0, p1 = h2f(hv.y)*w0, p2 = h2f(hv.z)*w0, p3 = h2f(hv.w)*w0;
  float q0=0.f,q1=0.f,q2=0.f,q3=0.f, r0=0.f,r1=0.f,r2=0.f,r3=0.f, t0=0.f,t1=0.f,t2=0.f,t3=0.f;
  int e0 = row_off[i], e1 = row_off[i+1];
  int e = e0;
  for (; e + 4 <= e1; e += 4){
    int s0 = colv[e], s1 = colv[e+1], s2 = colv[e+2], s3 = colv[e+3];
    float wA = dinv[s0]*di, wB = dinv[s1]*di, wC = dinv[s2]*di, wD = dinv[s3]*di;
    ushort4 v0 = *(const ushort4*)(feat + (size_t)s0*256 + f0);
    ushort4 v1 = *(const ushort4*)(feat + (size_t)s1*256 + f0);
    ushort4 v2 = *(const ushort4*)(feat + (size_t)s2*256 + f0);
    ushort4 v3 = *(const ushort4*)(feat + (size_t)s3*256 + f0);
    p0 += h2f(v0.x)*wA; p1 += h2f(v0.y)*wA; p2 += h2f(v0.z)*wA; p3 += h2f(v0.w)*wA;
    q0 += h2f(v1.x)*wB; q1 += h2f(v1.y)*wB; q2 += h2f(v1.z)*wB; q3 += h2f(v1.w)*wB;
    r0 += h2f(v2.x)*wC; r1 += h2f(v2.y)*wC; r2 += h2f(v2.z)*wC; r3 += h2f(v2.w)*wC;
    t0 += h2f(v3.x)*wD; t1 += h2f(v3.y)*wD; t2 += h2f(v3.z)*wD; t3 += h2f(v3.w)*wD;
  }
  for (; e < e1; ++e){
    int s = colv[e];
    float w = dinv[s]*di;
    ushort4 v = *(const ushort4*)(feat + (size_t)s*256 + f0);
    p0 += h2f(v.x)*w; p1 += h2f(v.y)*w; p2 += h2f(v.z)*w; p3 += h2f(v.w)*w;
  }
  float a0 = p0+q0+r0+t0, a1 = p1+q1+r1+t1, a2 = p2+q2+r2+t2, a3 = p3+q3+r3+t3;
  float4 o;
  if (f0 < 128){
    float4 bb = *(const float4*)(bmu + f0);
    o.x = a0 + bb.x; o.y = a1 + bb.y; o.z = a2 + bb.z; o.w = a3 + bb.w;
    *(float4*)(outp + (size_t)i*128 + f0) = o;
  } else {
    int g = f0 - 128;
    float4 bb = *(const float4*)(bls + g);
    o.x = a0 + bb.x; o.y = a1 + bb.y; o.z = a2 + bb.z; o.w = a3 + bb.w;
    *(float4*)(outp + (size_t)NN*128 + (size_t)i*128 + g) = o;
  }
}

extern "C" void kernel_launch(void* const* d_in, const int* in_sizes, int n_in,
                              void* d_out, int out_size, void* d_ws, size_t ws_size,
                              hipStream_t stream){
  const float* x   = (const float*)d_in[0];
  const int* eidx  = (const int*)d_in[1];
  const float* W1  = (const float*)d_in[2];
  const float* b1  = (const float*)d_in[3];
  const float* Wmu = (const float*)d_in[4];
  const float* bmu = (const float*)d_in[5];
  const float* Wls = (const float*)d_in[6];
  const float* bls = (const float*)d_in[7];
  float* out = (float*)d_out;

  char* ws = (char*)d_ws;
  size_t off = 0;
  auto alloc = [&](size_t bytes)->char*{
    char* p = ws + off; off = (off + bytes + 511) & ~(size_t)511; return p;
  };
  int* cnt      = (int*)alloc(NN*4);
  float* dinv   = (float*)alloc(NN*4);
  int* row_off  = (int*)alloc((NN+1)*4);
  int* cursor   = (int*)alloc(NN*4);
  int* bsum     = (int*)alloc(128*4);
  int* colv     = (int*)alloc(EE*4);
  unsigned short* Bt1 = (unsigned short*)alloc((size_t)256*512*2);
  unsigned short* Bt2 = (unsigned short*)alloc((size_t)256*512*2);
  unsigned short* AspX = (unsigned short*)alloc((size_t)NN*512*2);
  unsigned short* H1sp = (unsigned short*)alloc((size_t)NN*512*2);
  unsigned short* h = (unsigned short*)alloc((size_t)NN*256*2);  // fp16
  unsigned short* z = h;   // h dead after k_agg_relu; reuse for z

  hipMemsetAsync(cnt, 0, NN*4, stream);
  k_count<<<(EE+255)/256, 256, 0, stream>>>(eidx, cnt);
  k_scanA<<<98, 512, 0, stream>>>(cnt, bsum);
  k_scanB<<<1, 128, 0, stream>>>(bsum, row_off);
  k_scanC<<<98, 512, 0, stream>>>(cnt, bsum, row_off, cursor, dinv);
  k_fill<<<(EE+255)/256, 256, 0, stream>>>(eidx, cursor, colv);
  k_prepB<<<512, 256, 0, stream>>>(W1, Wmu, Wls, Bt1, Bt2);
  k_prepA<<<12500, 256, 0, stream>>>(x, AspX);
  k_gemm<<<dim3(391, 2), 256, 0, stream>>>(AspX, Bt1, h, NN);
  k_agg_relu<<<12500, 256, 0, stream>>>(h, dinv, row_off, colv, b1, H1sp);
  k_gemm<<<dim3(391, 2), 256, 0, stream>>>(H1sp, Bt2, z, NN);
  k_agg_out<<<12500, 256, 0, stream>>>(z, dinv, row_off, colv, bmu, bls, out);
}

// Round 6
// 378.037 us; speedup vs baseline: 1.4756x; 1.0503x over previous
//
#include <hip/hip_runtime.h>

#define NN 50000
#define EE 800000

typedef _Float16 half8 __attribute__((ext_vector_type(8)));
typedef float f32x4 __attribute__((ext_vector_type(4)));

__device__ __forceinline__ unsigned short f2h(float f){
  _Float16 h = (_Float16)f; unsigned short u; __builtin_memcpy(&u, &h, 2); return u;
}
__device__ __forceinline__ float h2f(unsigned short u){
  _Float16 h; __builtin_memcpy(&h, &u, 2); return (float)h;
}
// split f32 -> interleaved fp16 {hi, lo} at p (hi+lo == v to ~2^-24 rel)
__device__ __forceinline__ void split2h(float v, unsigned short* p){
  _Float16 hi = (_Float16)v;
  _Float16 lo = (_Float16)(v - (float)hi);
  __builtin_memcpy(p, &hi, 2);
  __builtin_memcpy(p+1, &lo, 2);
}
// async 16B global->LDS; LDS dest = wave-uniform base + lane*16
__device__ __forceinline__ void gl2lds16(const unsigned short* g, unsigned short* l){
  __builtin_amdgcn_global_load_lds(
    (const __attribute__((address_space(1))) unsigned int*)g,
    (__attribute__((address_space(3))) unsigned int*)l, 16, 0, 0);
}

// layout probe: 1 if edge_index is int64 (odd int32 words all zero)
__device__ __forceinline__ int detect_m(const int* eidx, int* sh){
  int t = threadIdx.x;
  if (t < 64){
    int v = eidx[2*t + 1];
    unsigned long long nz = __ballot(v != 0);
    if (t == 0) *sh = (nz == 0ULL) ? 1 : 0;
  }
  __syncthreads();
  return *sh;
}

__global__ void k_count(const int* __restrict__ eidx, int* __restrict__ cnt){
  __shared__ int msh;
  int m = detect_m(eidx, &msh);
  int e = blockIdx.x*256 + threadIdx.x;
  if (e >= EE) return;
  int d = m ? eidx[2*(EE + e)] : eidx[EE + e];
  atomicAdd(&cnt[d], 1);
}

// ---- 3-stage multi-block scan ----
__global__ void k_scanA(const int* __restrict__ cnt, int* __restrict__ bsum){
  __shared__ int s[512];
  int tid = threadIdx.x;
  int i = blockIdx.x*512 + tid;
  s[tid] = (i < NN) ? cnt[i] : 0;
  __syncthreads();
  for (int off = 256; off >= 1; off >>= 1){
    if (tid < off) s[tid] += s[tid + off];
    __syncthreads();
  }
  if (tid == 0) bsum[blockIdx.x] = s[0];
}

__global__ void k_scanB(int* bsum, int* row_off){
  __shared__ int s[128];
  int tid = threadIdx.x;
  int v = (tid < 98) ? bsum[tid] : 0;
  s[tid] = v;
  __syncthreads();
  for (int off = 1; off < 128; off <<= 1){
    int t = (tid >= off) ? s[tid - off] : 0;
    __syncthreads();
    s[tid] += t;
    __syncthreads();
  }
  if (tid < 98) bsum[tid] = s[tid] - v;
  if (tid == 0) row_off[NN] = s[127];
}

__global__ void k_scanC(const int* __restrict__ cnt, const int* __restrict__ bsum,
                        int* __restrict__ row_off, int* __restrict__ cursor,
                        float* __restrict__ dinv){
  __shared__ int s[512];
  int tid = threadIdx.x;
  int i = blockIdx.x*512 + tid;
  int v = (i < NN) ? cnt[i] : 0;
  s[tid] = v;
  __syncthreads();
  for (int off = 1; off < 512; off <<= 1){
    int t = (tid >= off) ? s[tid - off] : 0;
    __syncthreads();
    s[tid] += t;
    __syncthreads();
  }
  if (i < NN){
    int val = bsum[blockIdx.x] + s[tid] - v;
    row_off[i] = val;
    cursor[i]  = val;
    dinv[i]    = rsqrtf((float)(v + 1));
  }
}

// fill CSR with fused per-edge norm: edges[p] = {src, dinv[src]*dinv[dst]}
__global__ void k_fill(const int* __restrict__ eidx, const float* __restrict__ dinv,
                       int* __restrict__ cursor, int2* __restrict__ edges){
  __shared__ int msh;
  int m = detect_m(eidx, &msh);
  int e = blockIdx.x*256 + threadIdx.x;
  if (e >= EE) return;
  int sv = m ? eidx[2*e]        : eidx[e];
  int d  = m ? eidx[2*(EE + e)] : eidx[EE + e];
  float w = dinv[sv]*dinv[d];
  int p = atomicAdd(&cursor[d], 1);
  int2 ed; ed.x = sv; ed.y = __float_as_int(w);
  edges[p] = ed;
}

// ---- B prep: Bt1 = fp16 dup pairs [n][512]; Bt2 = plain fp16 [n][256] ----
__global__ void k_prepB(const float* __restrict__ W1, const float* __restrict__ Wmu,
                        const float* __restrict__ Wls, unsigned short* __restrict__ Bt1,
                        unsigned short* __restrict__ Bt2){
  int gid = blockIdx.x*256 + threadIdx.x;   // 131072
  int idx = gid & 65535;
  int n = idx & 255, k = idx >> 8;
  if (gid < 65536){
    unsigned short h = f2h(W1[k*256 + n]);
    unsigned short* p = Bt1 + (size_t)n*512 + 2*k;
    p[0] = h; p[1] = h;
  } else {
    float w = (n < 128) ? Wmu[k*128 + n] : Wls[k*128 + (n - 128)];
    Bt2[(size_t)n*256 + k] = f2h(w);
  }
}

// ---- A prep: f32 x -> interleaved fp16-split [r][512], per k {hi,lo} ----
__global__ __launch_bounds__(256) void k_prepA(const float* __restrict__ X,
                                               unsigned short* __restrict__ Asp){
  int gid = blockIdx.x*256 + threadIdx.x;
  int r = gid >> 6, t = gid & 63;
  if (r >= NN) return;
  float4 v = *(const float4*)(X + (size_t)r*256 + t*4);
  __attribute__((aligned(16))) unsigned short sh[8];
  split2h(v.x, sh); split2h(v.y, sh+2); split2h(v.z, sh+4); split2h(v.w, sh+6);
  *(uint4*)(Asp + (size_t)r*512 + t*8) = *(const uint4*)(sh);
}

// ---- 128x128 tile fp16 MFMA GEMM, async global_load_lds staging + XOR swizzle ----
// A stride = B stride = KT*64 shorts. fp16 C out (stride 256).
// LDS layout: slot for (row r, orig chunk c of 8 shorts) = r*64 + (c ^ (r&7))*8.
template<int KT>
__global__ __launch_bounds__(256) void k_gemm(const unsigned short* __restrict__ Asp,
                                              const unsigned short* __restrict__ Bt,
                                              unsigned short* __restrict__ C, int M){
  __shared__ __align__(16) unsigned short sA[128*64];
  __shared__ __align__(16) unsigned short sB[128*64];
  const int tid  = threadIdx.x;
  const int wave = tid >> 6, lane = tid & 63;
  const int wm = wave >> 1, wn = wave & 1;
  const int quad = lane >> 4, l16 = lane & 15;
  const int tM = blockIdx.x, tN = blockIdx.y;
  const int rsub = lane >> 3;              // 0..7
  const int chs  = (lane & 7) ^ rsub;      // swizzled chunk this lane fetches

  f32x4 acc[4][4] = {};

  for (int kt = 0; kt < KT; ++kt){
    #pragma unroll
    for (int j = 0; j < 4; ++j){
      int q = wave*4 + j;                  // 0..15 (8 rows per instr)
      int r = q*8 + rsub;
      int arow = tM*128 + r; if (arow >= M) arow = M-1;
      gl2lds16(Asp + (size_t)arow*(KT*64) + kt*64 + chs*8, &sA[q*512]);
      gl2lds16(Bt  + (size_t)(tN*128 + r)*(KT*64) + kt*64 + chs*8, &sB[q*512]);
    }
    __syncthreads();
    #pragma unroll
    for (int ks = 0; ks < 2; ++ks){
      half8 af[4], bfr[4];
      #pragma unroll
      for (int t = 0; t < 4; ++t){
        int R = wm*64 + t*16 + l16;
        af[t]  = *(const half8*)(&sA[R*64 + ((ks*4 + quad) ^ (R & 7))*8]);
      }
      #pragma unroll
      for (int t = 0; t < 4; ++t){
        int R = wn*64 + t*16 + l16;
        bfr[t] = *(const half8*)(&sB[R*64 + ((ks*4 + quad) ^ (R & 7))*8]);
      }
      #pragma unroll
      for (int mt = 0; mt < 4; ++mt)
        #pragma unroll
        for (int nt = 0; nt < 4; ++nt)
          acc[mt][nt] = __builtin_amdgcn_mfma_f32_16x16x32_f16(af[mt], bfr[nt], acc[mt][nt], 0, 0, 0);
    }
    __syncthreads();
  }

  #pragma unroll
  for (int mt = 0; mt < 4; ++mt){
    #pragma unroll
    for (int r = 0; r < 4; ++r){
      int row = tM*128 + wm*64 + mt*16 + quad*4 + r;
      if (row < M){
        #pragma unroll
        for (int nt = 0; nt < 4; ++nt){
          int cc = tN*128 + wn*64 + nt*16 + l16;
          C[(size_t)row*256 + cc] = f2h(acc[mt][nt][r]);
        }
      }
    }
  }
}

// ---- agg layer1: fp16 gather-sum (unroll 8), +bias, relu, write plain fp16 ----
__global__ __launch_bounds__(256) void k_agg_relu(const unsigned short* __restrict__ feat,
    const float* __restrict__ dinv, const int* __restrict__ row_off, const int2* __restrict__ edges,
    const float* __restrict__ b1, unsigned short* __restrict__ h1){
  int i = blockIdx.x*4 + (threadIdx.x >> 6);
  if (i >= NN) return;
  int lane = threadIdx.x & 63;
  int f0 = lane*4;
  float di = dinv[i];
  float w0 = di*di;
  ushort4 hv = *(const ushort4*)(feat + (size_t)i*256 + f0);
  float p0 = h2f(hv.x)*w0, p1 = h2f(hv.y)*w0, p2 = h2f(hv.z)*w0, p3 = h2f(hv.w)*w0;
  float q0=0.f,q1=0.f,q2=0.f,q3=0.f, r0=0.f,r1=0.f,r2=0.f,r3=0.f, t0=0.f,t1=0.f,t2=0.f,t3=0.f;
  int e0 = row_off[i], e1 = row_off[i+1];
  int e = e0;
  for (; e + 8 <= e1; e += 8){
    int2 ed0 = edges[e],   ed1 = edges[e+1], ed2 = edges[e+2], ed3 = edges[e+3];
    int2 ed4 = edges[e+4], ed5 = edges[e+5], ed6 = edges[e+6], ed7 = edges[e+7];
    ushort4 v0 = *(const ushort4*)(feat + (size_t)ed0.x*256 + f0);
    ushort4 v1 = *(const ushort4*)(feat + (size_t)ed1.x*256 + f0);
    ushort4 v2 = *(const ushort4*)(feat + (size_t)ed2.x*256 + f0);
    ushort4 v3 = *(const ushort4*)(feat + (size_t)ed3.x*256 + f0);
    ushort4 v4 = *(const ushort4*)(feat + (size_t)ed4.x*256 + f0);
    ushort4 v5 = *(const ushort4*)(feat + (size_t)ed5.x*256 + f0);
    ushort4 v6 = *(const ushort4*)(feat + (size_t)ed6.x*256 + f0);
    ushort4 v7 = *(const ushort4*)(feat + (size_t)ed7.x*256 + f0);
    float wA = __int_as_float(ed0.y), wB = __int_as_float(ed1.y);
    float wC = __int_as_float(ed2.y), wD = __int_as_float(ed3.y);
    float wE = __int_as_float(ed4.y), wF = __int_as_float(ed5.y);
    float wG = __int_as_float(ed6.y), wH = __int_as_float(ed7.y);
    p0 += h2f(v0.x)*wA; p1 += h2f(v0.y)*wA; p2 += h2f(v0.z)*wA; p3 += h2f(v0.w)*wA;
    q0 += h2f(v1.x)*wB; q1 += h2f(v1.y)*wB; q2 += h2f(v1.z)*wB; q3 += h2f(v1.w)*wB;
    r0 += h2f(v2.x)*wC; r1 += h2f(v2.y)*wC; r2 += h2f(v2.z)*wC; r3 += h2f(v2.w)*wC;
    t0 += h2f(v3.x)*wD; t1 += h2f(v3.y)*wD; t2 += h2f(v3.z)*wD; t3 += h2f(v3.w)*wD;
    p0 += h2f(v4.x)*wE; p1 += h2f(v4.y)*wE; p2 += h2f(v4.z)*wE; p3 += h2f(v4.w)*wE;
    q0 += h2f(v5.x)*wF; q1 += h2f(v5.y)*wF; q2 += h2f(v5.z)*wF; q3 += h2f(v5.w)*wF;
    r0 += h2f(v6.x)*wG; r1 += h2f(v6.y)*wG; r2 += h2f(v6.z)*wG; r3 += h2f(v6.w)*wG;
    t0 += h2f(v7.x)*wH; t1 += h2f(v7.y)*wH; t2 += h2f(v7.z)*wH; t3 += h2f(v7.w)*wH;
  }
  for (; e < e1; ++e){
    int2 ed = edges[e];
    float w = __int_as_float(ed.y);
    ushort4 v = *(const ushort4*)(feat + (size_t)ed.x*256 + f0);
    p0 += h2f(v.x)*w; p1 += h2f(v.y)*w; p2 += h2f(v.z)*w; p3 += h2f(v.w)*w;
  }
  float4 bb = *(const float4*)(b1 + f0);
  ushort4 o;
  o.x = f2h(fmaxf(p0+q0+r0+t0 + bb.x, 0.f));
  o.y = f2h(fmaxf(p1+q1+r1+t1 + bb.y, 0.f));
  o.z = f2h(fmaxf(p2+q2+r2+t2 + bb.z, 0.f));
  o.w = f2h(fmaxf(p3+q3+r3+t3 + bb.w, 0.f));
  *(ushort4*)(h1 + (size_t)i*256 + f0) = o;
}

// ---- agg layer2: fp16 gather-sum (unroll 8), +bias, write mu/logstd f32 ----
__global__ __launch_bounds__(256) void k_agg_out(const unsigned short* __restrict__ feat,
    const float* __restrict__ dinv, const int* __restrict__ row_off, const int2* __restrict__ edges,
    const float* __restrict__ bmu, const float* __restrict__ bls, float* __restrict__ outp){
  int i = blockIdx.x*4 + (threadIdx.x >> 6);
  if (i >= NN) return;
  int lane = threadIdx.x & 63;
  int f0 = lane*4;
  float di = dinv[i];
  float w0 = di*di;
  ushort4 hv = *(const ushort4*)(feat + (size_t)i*256 + f0);
  float p0 = h2f(hv.x)*w0, p1 = h2f(hv.y)*w0, p2 = h2f(hv.z)*w0, p3 = h2f(hv.w)*w0;
  float q0=0.f,q1=0.f,q2=0.f,q3=0.f, r0=0.f,r1=0.f,r2=0.f,r3=0.f, t0=0.f,t1=0.f,t2=0.f,t3=0.f;
  int e0 = row_off[i], e1 = row_off[i+1];
  int e = e0;
  for (; e + 8 <= e1; e += 8){
    int2 ed0 = edges[e],   ed1 = edges[e+1], ed2 = edges[e+2], ed3 = edges[e+3];
    int2 ed4 = edges[e+4], ed5 = edges[e+5], ed6 = edges[e+6], ed7 = edges[e+7];
    ushort4 v0 = *(const ushort4*)(feat + (size_t)ed0.x*256 + f0);
    ushort4 v1 = *(const ushort4*)(feat + (size_t)ed1.x*256 + f0);
    ushort4 v2 = *(const ushort4*)(feat + (size_t)ed2.x*256 + f0);
    ushort4 v3 = *(const ushort4*)(feat + (size_t)ed3.x*256 + f0);
    ushort4 v4 = *(const ushort4*)(feat + (size_t)ed4.x*256 + f0);
    ushort4 v5 = *(const ushort4*)(feat + (size_t)ed5.x*256 + f0);
    ushort4 v6 = *(const ushort4*)(feat + (size_t)ed6.x*256 + f0);
    ushort4 v7 = *(const ushort4*)(feat + (size_t)ed7.x*256 + f0);
    float wA = __int_as_float(ed0.y), wB = __int_as_float(ed1.y);
    float wC = __int_as_float(ed2.y), wD = __int_as_float(ed3.y);
    float wE = __int_as_float(ed4.y), wF = __int_as_float(ed5.y);
    float wG = __int_as_float(ed6.y), wH = __int_as_float(ed7.y);
    p0 += h2f(v0.x)*wA; p1 += h2f(v0.y)*wA; p2 += h2f(v0.z)*wA; p3 += h2f(v0.w)*wA;
    q0 += h2f(v1.x)*wB; q1 += h2f(v1.y)*wB; q2 += h2f(v1.z)*wB; q3 += h2f(v1.w)*wB;
    r0 += h2f(v2.x)*wC; r1 += h2f(v2.y)*wC; r2 += h2f(v2.z)*wC; r3 += h2f(v2.w)*wC;
    t0 += h2f(v3.x)*wD; t1 += h2f(v3.y)*wD; t2 += h2f(v3.z)*wD; t3 += h2f(v3.w)*wD;
    p0 += h2f(v4.x)*wE; p1 += h2f(v4.y)*wE; p2 += h2f(v4.z)*wE; p3 += h2f(v4.w)*wE;
    q0 += h2f(v5.x)*wF; q1 += h2f(v5.y)*wF; q2 += h2f(v5.z)*wF; q3 += h2f(v5.w)*wF;
    r0 += h2f(v6.x)*wG; r1 += h2f(v6.y)*wG; r2 += h2f(v6.z)*wG; r3 += h2f(v6.w)*wG;
    t0 += h2f(v7.x)*wH; t1 += h2f(v7.y)*wH; t2 += h2f(v7.z)*wH; t3 += h2f(v7.w)*wH;
  }
  for (; e < e1; ++e){
    int2 ed = edges[e];
    float w = __int_as_float(ed.y);
    ushort4 v = *(const ushort4*)(feat + (size_t)ed.x*256 + f0);
    p0 += h2f(v.x)*w; p1 += h2f(v.y)*w; p2 += h2f(v.z)*w; p3 += h2f(v.w)*w;
  }
  float a0 = p0+q0+r0+t0, a1 = p1+q1+r1+t1, a2 = p2+q2+r2+t2, a3 = p3+q3+r3+t3;
  float4 o;
  if (f0 < 128){
    float4 bb = *(const float4*)(bmu + f0);
    o.x = a0 + bb.x; o.y = a1 + bb.y; o.z = a2 + bb.z; o.w = a3 + bb.w;
    *(float4*)(outp + (size_t)i*128 + f0) = o;
  } else {
    int g = f0 - 128;
    float4 bb = *(const float4*)(bls + g);
    o.x = a0 + bb.x; o.y = a1 + bb.y; o.z = a2 + bb.z; o.w = a3 + bb.w;
    *(float4*)(outp + (size_t)NN*128 + (size_t)i*128 + g) = o;
  }
}

extern "C" void kernel_launch(void* const* d_in, const int* in_sizes, int n_in,
                              void* d_out, int out_size, void* d_ws, size_t ws_size,
                              hipStream_t stream){
  const float* x   = (const float*)d_in[0];
  const int* eidx  = (const int*)d_in[1];
  const float* W1  = (const float*)d_in[2];
  const float* b1  = (const float*)d_in[3];
  const float* Wmu = (const float*)d_in[4];
  const float* bmu = (const float*)d_in[5];
  const float* Wls = (const float*)d_in[6];
  const float* bls = (const float*)d_in[7];
  float* out = (float*)d_out;

  char* ws = (char*)d_ws;
  size_t off = 0;
  auto alloc = [&](size_t bytes)->char*{
    char* p = ws + off; off = (off + bytes + 511) & ~(size_t)511; return p;
  };
  int* cnt      = (int*)alloc(NN*4);
  float* dinv   = (float*)alloc(NN*4);
  int* row_off  = (int*)alloc((NN+1)*4);
  int* cursor   = (int*)alloc(NN*4);
  int* bsum     = (int*)alloc(128*4);
  int2* edges   = (int2*)alloc((size_t)EE*8);
  unsigned short* Bt1 = (unsigned short*)alloc((size_t)256*512*2);
  unsigned short* Bt2 = (unsigned short*)alloc((size_t)256*256*2);
  unsigned short* AspX = (unsigned short*)alloc((size_t)NN*512*2);
  unsigned short* h1  = (unsigned short*)alloc((size_t)NN*256*2);  // fp16
  unsigned short* h   = (unsigned short*)alloc((size_t)NN*256*2);  // fp16
  unsigned short* z   = h;   // h dead after k_agg_relu; reuse for z

  hipMemsetAsync(cnt, 0, NN*4, stream);
  k_count<<<(EE+255)/256, 256, 0, stream>>>(eidx, cnt);
  k_scanA<<<98, 512, 0, stream>>>(cnt, bsum);
  k_scanB<<<1, 128, 0, stream>>>(bsum, row_off);
  k_scanC<<<98, 512, 0, stream>>>(cnt, bsum, row_off, cursor, dinv);
  k_fill<<<(EE+255)/256, 256, 0, stream>>>(eidx, dinv, cursor, edges);
  k_prepB<<<512, 256, 0, stream>>>(W1, Wmu, Wls, Bt1, Bt2);
  k_prepA<<<12500, 256, 0, stream>>>(x, AspX);
  k_gemm<8><<<dim3(391, 2), 256, 0, stream>>>(AspX, Bt1, h, NN);
  k_agg_relu<<<12500, 256, 0, stream>>>(h, dinv, row_off, edges, b1, h1);
  k_gemm<4><<<dim3(391, 2), 256, 0, stream>>>(h1, Bt2, z, NN);
  k_agg_out<<<12500, 256, 0, stream>>>(z, dinv, row_off, edges, bmu, bls, out);
}